// Round 1
// baseline (912.054 us; speedup 1.0000x reference)
//
#include <hip/hip_runtime.h>
#include <stdint.h>

// ROUND 5: f32 restructure (no precision risk, no MFMA yet).
//
// K1 qkv_gemm: M=8 row-tile per block, X staged in LDS (16 KB), thread = output
//              feature o with acc[8]; W read as per-thread contiguous float4
//              (each W element reused 8x -> L2 W-traffic /8). 768 blocks.
// K2 attn_f32: block=(b,q), 8 waves = 8 heads. rels tile (64x64, pad 68) staged
//              in LDS once per k-tile and shared by all 8 waves (was: 8x L2
//              re-read per phase). float4 dot products; phase-3 4-accum chains.
//
// Same ws layout as round 4 (12 MB q/k/v in (B,H,L,DH) f32).

// ---------------------------------------------------------------- K1 ---
__global__ __launch_bounds__(512, 4)
void qkv_gemm(const float* __restrict__ X,
              const float* __restrict__ Wq, const float* __restrict__ bq,
              const float* __restrict__ Wk, const float* __restrict__ bk,
              const float* __restrict__ Wv, const float* __restrict__ bv,
              float* __restrict__ qf, float* __restrict__ kf, float* __restrict__ vf)
{
    __shared__ __align__(16) float Xs[8][512];      // 16 KB
    const int z  = blockIdx.y;                      // 0=q 1=k 2=v
    const int m0 = blockIdx.x * 8;                  // first row (bl) of tile
    const float* W  = (z==0) ? Wq : (z==1) ? Wk : Wv;
    const float* bb = (z==0) ? bq : (z==1) ? bk : bv;
    float* dst      = (z==0) ? qf : (z==1) ? kf : vf;

    const int t = threadIdx.x;
    // stage 8 rows of X: thread t -> row t>>6, 8 consecutive floats at (t&63)*8
    {
        const int r = t >> 6, c = (t & 63) * 8;
        const float4* src = (const float4*)(X + (size_t)(m0 + r)*512 + c);
        float4 a = src[0], b4 = src[1];
        *(float4*)(&Xs[r][c])     = a;
        *(float4*)(&Xs[r][c + 4]) = b4;
    }
    __syncthreads();

    const int o = t;                                // output feature
    const float* wrow = W + (size_t)o * 512;
    float acc[8] = {0.f,0.f,0.f,0.f,0.f,0.f,0.f,0.f};

    #pragma unroll 4
    for (int k = 0; k < 512; k += 4) {
        const float4 w4 = *(const float4*)(wrow + k);
        #pragma unroll
        for (int m = 0; m < 8; m++) {
            const float4 x4 = *(const float4*)(&Xs[m][k]);   // LDS broadcast
            acc[m] = fmaf(x4.x, w4.x, acc[m]);
            acc[m] = fmaf(x4.y, w4.y, acc[m]);
            acc[m] = fmaf(x4.z, w4.z, acc[m]);
            acc[m] = fmaf(x4.w, w4.w, acc[m]);
        }
    }

    const float bo = bb[o];
    const int h = o >> 6, d = o & 63;
    #pragma unroll
    for (int m = 0; m < 8; m++) {
        const int bl = m0 + m;                      // tiles never cross b (512%8==0)
        const int b = bl >> 9, l = bl & 511;
        dst[((size_t)(b*8 + h)*512 + l)*64 + d] = acc[m] + bo;   // (B,H,L,DH)
    }
}

// ---------------------------------------------------------------- K2 ---
__global__ __launch_bounds__(512, 4)
void attn_f32(const float* __restrict__ qf, const float* __restrict__ kf,
              const float* __restrict__ vf, const float* __restrict__ rels,
              const float* __restrict__ heads, float* __restrict__ out)
{
    __shared__ __align__(16) float S[8*512];        // 16 KB: scores/probs, row per head
    __shared__ __align__(16) float qs[8*64];        // 2 KB
    __shared__ __align__(16) float rl[64*68];       // 17 KB: rels k-tile, pad 68

    const int bq = blockIdx.x;                      // b*512 + q
    const int b = bq >> 9, q = bq & 511;
    const int t = threadIdx.x;
    const int h = t >> 6, lane = t & 63;

    qs[t] = qf[((size_t)(b*8 + h)*512 + q)*64 + lane];

    const float* relrow = rels  + ((size_t)(b*512 + q)*512)*64;   // [512][64]
    const float* hrow   = heads + ((size_t)b*512 + q)*512;

    // ---- phase 1: scores; rels tile staged in LDS, shared by all 8 waves
    for (int kt = 0; kt < 8; kt++) {
        __syncthreads();                            // rl free to overwrite
        {
            const int r = t >> 3, c = (t & 7) * 8;  // 64 rows x 64 cols
            const float4* src = (const float4*)(relrow + (size_t)(kt*64 + r)*64 + c);
            float4 a = src[0], b4 = src[1];
            *(float4*)(&rl[r*68 + c])     = a;
            *(float4*)(&rl[r*68 + c + 4]) = b4;
        }
        __syncthreads();                            // rl ready (and qs on kt==0)

        const int k = kt*64 + lane;
        const float* krow = kf + ((size_t)(b*8 + h)*512 + k)*64;
        const float* qrow = qs + h*64;
        const float* rrow = rl + lane*68;           // pad-68: bank-conflict ~free
        float a0=0.f, a1=0.f, a2=0.f, a3=0.f;
        #pragma unroll
        for (int d = 0; d < 64; d += 8) {
            const float4 qa = *(const float4*)(qrow + d);
            const float4 ka = *(const float4*)(krow + d);
            const float4 ra = *(const float4*)(rrow + d);
            const float4 qb = *(const float4*)(qrow + d + 4);
            const float4 kb = *(const float4*)(krow + d + 4);
            const float4 rb = *(const float4*)(rrow + d + 4);
            a0 = fmaf(qa.x, ka.x, a0); a1 = fmaf(qa.x, ra.x, a1);
            a0 = fmaf(qa.y, ka.y, a0); a1 = fmaf(qa.y, ra.y, a1);
            a0 = fmaf(qa.z, ka.z, a0); a1 = fmaf(qa.z, ra.z, a1);
            a0 = fmaf(qa.w, ka.w, a0); a1 = fmaf(qa.w, ra.w, a1);
            a2 = fmaf(qb.x, kb.x, a2); a3 = fmaf(qb.x, rb.x, a3);
            a2 = fmaf(qb.y, kb.y, a2); a3 = fmaf(qb.y, rb.y, a3);
            a2 = fmaf(qb.z, kb.z, a2); a3 = fmaf(qb.z, rb.z, a3);
            a2 = fmaf(qb.w, kb.w, a2); a3 = fmaf(qb.w, rb.w, a3);
        }
        S[h*512 + k] = ((a0+a2) + (a1+a3))*0.125f + hrow[k];
    }

    // ---- phase 2: softmax (wave h owns S row h; no cross-wave reads)
    float mx = -3.0e38f;
    #pragma unroll
    for (int i = 0; i < 8; i++) mx = fmaxf(mx, S[h*512 + lane + 64*i]);
    #pragma unroll
    for (int w = 1; w < 64; w <<= 1) mx = fmaxf(mx, __shfl_xor(mx, w));
    float sum = 0.f;
    #pragma unroll
    for (int i = 0; i < 8; i++) {
        const float e = __expf(S[h*512 + lane + 64*i] - mx);
        S[h*512 + lane + 64*i] = e;
        sum += e;
    }
    #pragma unroll
    for (int w = 1; w < 64; w <<= 1) sum += __shfl_xor(sum, w);
    const float inv = 1.f / sum;

    // ---- phase 3: ctx = sum_k P*(v + rels); rels restaged per tile
    const int d = lane;
    const float* vcol = vf + ((size_t)(b*8 + h)*512)*64 + d;
    const float* Ph = S + h*512;
    float c0=0.f, c1=0.f, c2=0.f, c3=0.f;
    for (int kt = 0; kt < 8; kt++) {
        __syncthreads();                            // all waves done with prev rl
        {
            const int r = t >> 3, cc = (t & 7) * 8;
            const float4* src = (const float4*)(relrow + (size_t)(kt*64 + r)*64 + cc);
            float4 a = src[0], b4 = src[1];
            *(float4*)(&rl[r*68 + cc])     = a;
            *(float4*)(&rl[r*68 + cc + 4]) = b4;
        }
        __syncthreads();

        const int k0 = kt * 64;
        #pragma unroll 4
        for (int r = 0; r < 64; r += 4) {
            // rl[r*68+d]: fixed r, lanes d consecutive -> 2 lanes/bank (free)
            c0 = fmaf(Ph[k0+r+0], vcol[(size_t)(k0+r+0)*64] + rl[(r+0)*68 + d], c0);
            c1 = fmaf(Ph[k0+r+1], vcol[(size_t)(k0+r+1)*64] + rl[(r+1)*68 + d], c1);
            c2 = fmaf(Ph[k0+r+2], vcol[(size_t)(k0+r+2)*64] + rl[(r+2)*68 + d], c2);
            c3 = fmaf(Ph[k0+r+3], vcol[(size_t)(k0+r+3)*64] + rl[(r+3)*68 + d], c3);
        }
    }
    out[((size_t)b*512 + q)*512 + h*64 + d] = ((c0+c1) + (c2+c3)) * inv;
}

// --------------------------------------------------------------- launcher ---
extern "C" void kernel_launch(void* const* d_in, const int* in_sizes, int n_in,
                              void* d_out, int out_size, void* d_ws, size_t ws_size,
                              hipStream_t stream)
{
    (void)in_sizes; (void)n_in; (void)out_size; (void)ws_size;

    const float* hidden = (const float*)d_in[0];
    const float* heads  = (const float*)d_in[1];
    const float* rels   = (const float*)d_in[2];
    const float* Wq = (const float*)d_in[3];
    const float* bq = (const float*)d_in[4];
    const float* Wk = (const float*)d_in[5];
    const float* bk = (const float*)d_in[6];
    const float* Wv = (const float*)d_in[7];
    const float* bv = (const float*)d_in[8];
    float* outF = (float*)d_out;

    float* ws = (float*)d_ws;
    float* qf = ws;                 // (B,H,L,DH) f32, 4 MB
    float* kf = ws + 1048576;       // 4 MB
    float* vf = ws + 2097152;       // 4 MB; total 12 MB

    qkv_gemm<<<dim3(256, 3), 512, 0, stream>>>(
        hidden, Wq, bq, Wk, bk, Wv, bv, qf, kf, vf);

    attn_f32<<<dim3(2048), 512, 0, stream>>>(qf, kf, vf, rels, heads, outF);
}

// Round 2
// 611.831 us; speedup vs baseline: 1.4907x; 1.4907x over previous
//
#include <hip/hip_runtime.h>
#include <stdint.h>

// ROUND 6: coalescing rewrite (still pure f32).
//
// K0 wtrans:   WT[z][k][o] = W_z[o][k] via 64x64 LDS tiles. WT lives in d_out
//              (4 MB buffer, only needed before attn overwrites it) -> ws stays 12 MB.
// K1 qkv_gemm: thread=o, lanes read WT[k][o] COALESCED; X row-tile (8) in LDS,
//              broadcast b128 reads; acc[8]. K output stored TRANSPOSED:
//              kT[b,h,d,l] so attn's score loads are coalesced.
// K2 attn_f32: block=(b,q), 8 waves = 8 heads.
//              phase1: s = q.k (kT coalesced) + q.rel (rl LDS stride-65, bank-free)
//              phase2: per-wave softmax (unchanged)
//              phase3: ctx = sum_k P*(v + rel); v coalesced, rl column reads bank-free.

// ---------------------------------------------------------------- K0 ---
__global__ __launch_bounds__(256)
void wtrans(const float* __restrict__ Wq, const float* __restrict__ Wk,
            const float* __restrict__ Wv, float* __restrict__ WT)
{
    __shared__ float tile[64*65];
    const int z  = blockIdx.z;
    const float* W = (z==0) ? Wq : (z==1) ? Wk : Wv;
    const int kt = blockIdx.x * 64;                 // k-tile origin
    const int ot = blockIdx.y * 64;                 // o-tile origin
    const int t  = threadIdx.x;                     // 256

    // load: rows r of W (o-dim), coalesced 16 threads x float4 per row
    {
        const int c4 = (t & 15) * 4;                // k-offset
        #pragma unroll
        for (int i = 0; i < 4; i++) {
            const int r = (t >> 4) + i*16;          // o-offset
            const float4 v4 = *(const float4*)(W + (size_t)(ot + r)*512 + kt + c4);
            tile[r*65 + c4 + 0] = v4.x;
            tile[r*65 + c4 + 1] = v4.y;
            tile[r*65 + c4 + 2] = v4.z;
            tile[r*65 + c4 + 3] = v4.w;
        }
    }
    __syncthreads();

    // store: rows of WT (k-dim), coalesced; WT[k][o] = W[o][k] = tile[o][k]
    {
        const int c4 = (t & 15) * 4;                // o-offset
        float* dst = WT + (size_t)z*262144;
        #pragma unroll
        for (int i = 0; i < 4; i++) {
            const int r2 = (t >> 4) + i*16;         // k-offset
            float4 v4;
            v4.x = tile[(c4+0)*65 + r2];
            v4.y = tile[(c4+1)*65 + r2];
            v4.z = tile[(c4+2)*65 + r2];
            v4.w = tile[(c4+3)*65 + r2];
            *(float4*)(dst + (size_t)(kt + r2)*512 + ot + c4) = v4;
        }
    }
}

// ---------------------------------------------------------------- K1 ---
__global__ __launch_bounds__(512)
void qkv_gemm(const float* __restrict__ X, const float* __restrict__ WT,
              const float* __restrict__ bq, const float* __restrict__ bk,
              const float* __restrict__ bv,
              float* __restrict__ qf, float* __restrict__ kTb, float* __restrict__ vf)
{
    __shared__ __align__(16) float Xs[8][512];      // 16 KB
    const int z  = blockIdx.y;                      // 0=q 1=k 2=v
    const int m0 = blockIdx.x * 8;                  // first row (b*512+l)
    const float* WTz = WT + (size_t)z*262144;       // [512 k][512 o]
    const float* bb  = (z==0) ? bq : (z==1) ? bk : bv;

    const int t = threadIdx.x;
    {   // stage 8 X rows
        const int r = t >> 6, c = (t & 63) * 8;
        const float4* src = (const float4*)(X + (size_t)(m0 + r)*512 + c);
        float4 a = src[0], b4 = src[1];
        *(float4*)(&Xs[r][c])     = a;
        *(float4*)(&Xs[r][c + 4]) = b4;
    }
    __syncthreads();

    const int o = t;                                // output feature (lane-coalesced)
    float acc[8] = {0.f,0.f,0.f,0.f,0.f,0.f,0.f,0.f};

    #pragma unroll 4
    for (int k = 0; k < 512; k += 4) {
        const float w0 = WTz[(size_t)(k+0)*512 + o];    // coalesced b32
        const float w1 = WTz[(size_t)(k+1)*512 + o];
        const float w2 = WTz[(size_t)(k+2)*512 + o];
        const float w3 = WTz[(size_t)(k+3)*512 + o];
        #pragma unroll
        for (int m = 0; m < 8; m++) {
            const float4 x4 = *(const float4*)(&Xs[m][k]);   // LDS broadcast
            acc[m] = fmaf(x4.x, w0, acc[m]);
            acc[m] = fmaf(x4.y, w1, acc[m]);
            acc[m] = fmaf(x4.z, w2, acc[m]);
            acc[m] = fmaf(x4.w, w3, acc[m]);
        }
    }

    const float bo = bb[o];
    const int b = m0 >> 9, l0 = m0 & 511;
    const int h = o >> 6,  d = o & 63;
    if (z == 1) {
        // kT layout (B,H,DH,L): thread's 8 rows are 8 consecutive l -> 2 float4
        float* dst = kTb + ((size_t)(b*8 + h)*64 + d)*512 + l0;
        *(float4*)(dst + 0) = make_float4(acc[0]+bo, acc[1]+bo, acc[2]+bo, acc[3]+bo);
        *(float4*)(dst + 4) = make_float4(acc[4]+bo, acc[5]+bo, acc[6]+bo, acc[7]+bo);
    } else {
        float* dst = (z==0) ? qf : vf;              // (B,H,L,DH)
        #pragma unroll
        for (int m = 0; m < 8; m++)
            dst[((size_t)(b*8 + h)*512 + l0 + m)*64 + d] = acc[m] + bo;
    }
}

// ---------------------------------------------------------------- K2 ---
__global__ __launch_bounds__(512)
void attn_f32(const float* __restrict__ qf, const float* __restrict__ kT,
              const float* __restrict__ vf, const float* __restrict__ rels,
              const float* __restrict__ heads, float* __restrict__ out)
{
    __shared__ float S[8*512];                      // 16 KB scores/probs
    __shared__ __align__(16) float qs[8*64];        // 2 KB
    __shared__ float rl[64*65];                     // 16.25 KB, stride 65 (bank-free)

    const int bq = blockIdx.x;                      // b*512 + q
    const int b = bq >> 9, q = bq & 511;
    const int t = threadIdx.x;
    const int h = t >> 6, lane = t & 63;

    qs[t] = qf[((size_t)(b*8 + h)*512 + q)*64 + lane];

    const float* relrow = rels  + ((size_t)(b*512 + q)*512)*64;   // [512 k][64 d]
    const float* hrow   = heads + ((size_t)b*512 + q)*512;
    const float* kTh    = kT + ((size_t)(b*8 + h)*64)*512;        // [64 d][512 l]

    // ---- phase 1: scores
    for (int kt = 0; kt < 8; kt++) {
        __syncthreads();                            // rl free to overwrite
        {   // stage rels k-tile -> rl[k_local][d], stride 65
            const int r = t >> 3, c0 = (t & 7) * 8;
            const float4* src = (const float4*)(relrow + (size_t)(kt*64 + r)*64 + c0);
            const float4 A = src[0], B4 = src[1];
            float* w = rl + r*65 + c0;
            w[0]=A.x;  w[1]=A.y;  w[2]=A.z;  w[3]=A.w;
            w[4]=B4.x; w[5]=B4.y; w[6]=B4.z; w[7]=B4.w;
        }
        __syncthreads();                            // rl ready (qs too on kt==0)

        const int k = kt*64 + lane;
        const float* rrow = rl + lane*65;           // banks (lane+d)%32: free
        float aq0=0.f, aq1=0.f, ar0=0.f, ar1=0.f;
        #pragma unroll 4
        for (int d = 0; d < 64; d += 4) {
            const float4 q4 = *(const float4*)(qs + h*64 + d);   // broadcast
            const float k0 = kTh[(size_t)(d+0)*512 + k];         // coalesced
            const float k1 = kTh[(size_t)(d+1)*512 + k];
            const float k2 = kTh[(size_t)(d+2)*512 + k];
            const float k3 = kTh[(size_t)(d+3)*512 + k];
            aq0 = fmaf(q4.x, k0, aq0);
            aq1 = fmaf(q4.y, k1, aq1);
            aq0 = fmaf(q4.z, k2, aq0);
            aq1 = fmaf(q4.w, k3, aq1);
            ar0 = fmaf(q4.x, rrow[d+0], ar0);
            ar1 = fmaf(q4.y, rrow[d+1], ar1);
            ar0 = fmaf(q4.z, rrow[d+2], ar0);
            ar1 = fmaf(q4.w, rrow[d+3], ar1);
        }
        S[h*512 + k] = ((aq0+aq1) + (ar0+ar1))*0.125f + hrow[k];
    }
    // no barrier: S row h is written & read by wave h only

    // ---- phase 2: softmax over row h
    float mx = -3.0e38f;
    #pragma unroll
    for (int i = 0; i < 8; i++) mx = fmaxf(mx, S[h*512 + lane + 64*i]);
    #pragma unroll
    for (int w = 1; w < 64; w <<= 1) mx = fmaxf(mx, __shfl_xor(mx, w));
    float sum = 0.f;
    #pragma unroll
    for (int i = 0; i < 8; i++) {
        const float e = __expf(S[h*512 + lane + 64*i] - mx);
        S[h*512 + lane + 64*i] = e;
        sum += e;
    }
    #pragma unroll
    for (int w = 1; w < 64; w <<= 1) sum += __shfl_xor(sum, w);
    const float inv = 1.f / sum;

    // ---- phase 3: ctx = sum_k P*(v + rel)
    float c0=0.f, c1=0.f, c2=0.f, c3=0.f;
    for (int kt = 0; kt < 8; kt++) {
        __syncthreads();                            // all waves done with prev rl
        {
            const int r = t >> 3, cc = (t & 7) * 8;
            const float4* src = (const float4*)(relrow + (size_t)(kt*64 + r)*64 + cc);
            const float4 A = src[0], B4 = src[1];
            float* w = rl + r*65 + cc;
            w[0]=A.x;  w[1]=A.y;  w[2]=A.z;  w[3]=A.w;
            w[4]=B4.x; w[5]=B4.y; w[6]=B4.z; w[7]=B4.w;
        }
        __syncthreads();

        const float* vb = vf + ((size_t)(b*8 + h)*512 + kt*64)*64 + lane;  // d=lane
        const float* Ph = S + h*512 + kt*64;
        #pragma unroll 4
        for (int kk = 0; kk < 64; kk += 4) {
            const float4 p4 = *(const float4*)(Ph + kk);        // broadcast b128
            c0 = fmaf(p4.x, vb[(size_t)(kk+0)*64] + rl[(kk+0)*65 + lane], c0);
            c1 = fmaf(p4.y, vb[(size_t)(kk+1)*64] + rl[(kk+1)*65 + lane], c1);
            c2 = fmaf(p4.z, vb[(size_t)(kk+2)*64] + rl[(kk+2)*65 + lane], c2);
            c3 = fmaf(p4.w, vb[(size_t)(kk+3)*64] + rl[(kk+3)*65 + lane], c3);
        }
    }
    out[((size_t)b*512 + q)*512 + h*64 + lane] = ((c0+c1) + (c2+c3)) * inv;
}

// --------------------------------------------------------------- launcher ---
extern "C" void kernel_launch(void* const* d_in, const int* in_sizes, int n_in,
                              void* d_out, int out_size, void* d_ws, size_t ws_size,
                              hipStream_t stream)
{
    (void)in_sizes; (void)n_in; (void)out_size; (void)ws_size;

    const float* hidden = (const float*)d_in[0];
    const float* heads  = (const float*)d_in[1];
    const float* rels   = (const float*)d_in[2];
    const float* Wq = (const float*)d_in[3];
    const float* bq = (const float*)d_in[4];
    const float* Wk = (const float*)d_in[5];
    const float* bk = (const float*)d_in[6];
    const float* Wv = (const float*)d_in[7];
    const float* bv = (const float*)d_in[8];
    float* outF = (float*)d_out;

    float* ws = (float*)d_ws;
    float* qf  = ws;                 // (B,H,L,DH) f32, 4 MB
    float* kTb = ws + 1048576;       // (B,H,DH,L) f32, 4 MB  (transposed K)
    float* vf  = ws + 2097152;       // (B,H,L,DH) f32, 4 MB; total 12 MB

    // WT[3][512][512] lives in d_out (4 MB) -- consumed before attn overwrites it
    float* WT = outF;

    wtrans<<<dim3(8, 8, 3), 256, 0, stream>>>(Wq, Wk, Wv, WT);
    qkv_gemm<<<dim3(256, 3), 512, 0, stream>>>(hidden, WT, bq, bk, bv, qf, kTb, vf);
    attn_f32<<<dim3(2048), 512, 0, stream>>>(qf, kTb, vf, rels, heads, outF);
}

// Round 5
// 581.088 us; speedup vs baseline: 1.5696x; 1.0529x over previous
//
#include <hip/hip_runtime.h>
#include <stdint.h>

// ROUND 8: flash-fused attention (q-tile=4, online softmax, rels staged ONCE)
//          with FLOAT4-GRANULAR XOR swizzle so rel staging + phase-1 reads are
//          b128 LDS ops (was: all-scalar b32). qkv: 4 outputs/thread.
//
// K0 wtrans:   WT[z][k][o] = W_z[o][k] (in d_out, consumed before attn writes).
// K1 qkv_gemm: 256 thr, M=16 rows (Xs 32 KB), thread = 4 o's (stride 128) x 8 m.
//              K stored transposed kT[b,h,d,l].
// K2 attn_flash: block = (b, 4 q's), 8 waves = 8 heads. Per k-tile(64):
//              rel[4q][64k][64d] in LDS, word pos = k*64 + (d&3) + 4*((d>>2)^(k&15)):
//                - staging writes: 8x ds_write_b128 / thread
//                - phase-1 row reads (lane=k): ds_read_b128
//                - PV column reads (lane=d): b32, 2 lanes/bank (free)
//              online softmax in regs; PV P-broadcast via readlane (SGPR idx).

// ---------------------------------------------------------------- K0 ---
__global__ __launch_bounds__(256)
void wtrans(const float* __restrict__ Wq, const float* __restrict__ Wk,
            const float* __restrict__ Wv, float* __restrict__ WT)
{
    __shared__ float tile[64*65];
    const int z  = blockIdx.z;
    const float* W = (z==0) ? Wq : (z==1) ? Wk : Wv;
    const int kt = blockIdx.x * 64;
    const int ot = blockIdx.y * 64;
    const int t  = threadIdx.x;

    {
        const int c4 = (t & 15) * 4;
        #pragma unroll
        for (int i = 0; i < 4; i++) {
            const int r = (t >> 4) + i*16;
            const float4 v4 = *(const float4*)(W + (size_t)(ot + r)*512 + kt + c4);
            tile[r*65 + c4 + 0] = v4.x;
            tile[r*65 + c4 + 1] = v4.y;
            tile[r*65 + c4 + 2] = v4.z;
            tile[r*65 + c4 + 3] = v4.w;
        }
    }
    __syncthreads();
    {
        const int c4 = (t & 15) * 4;
        float* dst = WT + (size_t)z*262144;
        #pragma unroll
        for (int i = 0; i < 4; i++) {
            const int r2 = (t >> 4) + i*16;
            float4 v4;
            v4.x = tile[(c4+0)*65 + r2];
            v4.y = tile[(c4+1)*65 + r2];
            v4.z = tile[(c4+2)*65 + r2];
            v4.w = tile[(c4+3)*65 + r2];
            *(float4*)(dst + (size_t)(kt + r2)*512 + ot + c4) = v4;
        }
    }
}

// ---------------------------------------------------------------- K1 ---
__global__ __launch_bounds__(256)
void qkv_gemm(const float* __restrict__ X, const float* __restrict__ WT,
              const float* __restrict__ bq, const float* __restrict__ bk,
              const float* __restrict__ bv,
              float* __restrict__ qf, float* __restrict__ kTb, float* __restrict__ vf)
{
    __shared__ __align__(16) float Xs[16][512];     // 32 KB
    const int z  = blockIdx.y;
    const int m0 = blockIdx.x * 16;                 // 16-row tile (never crosses b)
    const float* WTz = WT + (size_t)z*262144;       // [512 k][512 o]
    const float* bb  = (z==0) ? bq : (z==1) ? bk : bv;

    const int t = threadIdx.x;
    {   // stage 16 X rows: thread t -> row t>>4, 32 consecutive floats
        const int r = t >> 4, c0 = (t & 15) * 32;
        const float4* src = (const float4*)(X + (size_t)(m0 + r)*512 + c0);
        float4* dstl = (float4*)(&Xs[r][c0]);
        #pragma unroll
        for (int i = 0; i < 8; i++) dstl[i] = src[i];
    }
    __syncthreads();

    const int ob   = t & 127;                       // o = ob + 128*j
    const int msub = (t >> 7) * 8;                  // 0 or 8
    float acc[8][4] = {};

    #pragma unroll 2
    for (int k = 0; k < 512; k += 4) {
        float w[4][4];
        #pragma unroll
        for (int kk = 0; kk < 4; kk++)
            #pragma unroll
            for (int j = 0; j < 4; j++)
                w[kk][j] = WTz[(size_t)(k+kk)*512 + ob + 128*j];   // coalesced
        #pragma unroll
        for (int mm = 0; mm < 8; mm++) {
            const float4 x4 = *(const float4*)(&Xs[msub + mm][k]); // broadcast
            #pragma unroll
            for (int j = 0; j < 4; j++) {
                acc[mm][j] = fmaf(x4.x, w[0][j], acc[mm][j]);
                acc[mm][j] = fmaf(x4.y, w[1][j], acc[mm][j]);
                acc[mm][j] = fmaf(x4.z, w[2][j], acc[mm][j]);
                acc[mm][j] = fmaf(x4.w, w[3][j], acc[mm][j]);
            }
        }
    }

    const int b     = m0 >> 9;
    const int lbase = (m0 & 511) + msub;
    #pragma unroll
    for (int j = 0; j < 4; j++) {
        const int o = ob + 128*j;
        const float bo = bb[o];
        const int h = o >> 6, d = o & 63;
        if (z == 1) {
            float* dst = kTb + ((size_t)(b*8 + h)*64 + d)*512 + lbase;
            *(float4*)(dst + 0) = make_float4(acc[0][j]+bo, acc[1][j]+bo,
                                              acc[2][j]+bo, acc[3][j]+bo);
            *(float4*)(dst + 4) = make_float4(acc[4][j]+bo, acc[5][j]+bo,
                                              acc[6][j]+bo, acc[7][j]+bo);
        } else {
            float* dst = ((z==0) ? qf : vf) + ((size_t)(b*8 + h)*512 + lbase)*64 + d;
            #pragma unroll
            for (int mm = 0; mm < 8; mm++) dst[(size_t)mm*64] = acc[mm][j] + bo;
        }
    }
}

// ---------------------------------------------------------------- K2 ---
__global__ __launch_bounds__(512)
void attn_flash(const float* __restrict__ qf, const float* __restrict__ kT,
                const float* __restrict__ vf, const float* __restrict__ rels,
                const float* __restrict__ heads, float* __restrict__ out)
{
    // rel tile [4 qi][64 k][64 d]; element (qi,k,d) at word
    //   qi*4096 + k*64 + (d&3) + 4*((d>>2) ^ (k&15))
    // 16B-aligned groups -> b128 staging writes + b128 phase-1 reads;
    // PV column reads (fixed k, lane=d) land 2 lanes/bank (free).
    __shared__ __align__(16) float rl[4*64*64];     // 64 KB -> 2 blocks/CU

    // XCD-aware swizzle (512 = 8 XCD * 64, bijective)
    const int bid = blockIdx.x;
    const int wg  = (bid & 7) * 64 + (bid >> 3);
    const int b   = wg >> 7;
    const int q0  = (wg & 127) * 4;

    const int t = threadIdx.x, h = t >> 6, lane = t & 63;

    const float* kTh = kT + ((size_t)(b*8 + h)*64)*512;        // [64 d][512 l]
    const float* vfh = vf + ((size_t)(b*8 + h)*512)*64;        // [512 k][64 d]
    const float* qh  = qf + ((size_t)(b*8 + h)*512 + q0)*64;   // [4 qi][64 d]

    float ctx[4] = {0.f, 0.f, 0.f, 0.f};
    float m[4]   = {-3.0e38f, -3.0e38f, -3.0e38f, -3.0e38f};
    float s[4]   = {0.f, 0.f, 0.f, 0.f};

    // staging mapping: thread -> (qi, k-row, d-half)
    const int sqi = t >> 7;                    // 0..3
    const int su  = t & 127;
    const int sk  = su >> 1;                   // 0..63
    const int sdh = (su & 1) * 32;             // 0 or 32
    const int sc4 = sdh >> 2;                  // float4-col base: 0 or 8
    const int skx = sk & 15;
    const float* srcq = rels + ((size_t)(b*512 + q0 + sqi))*512*64;
    float* wb = rl + sqi*4096 + sk*64;

    for (int kt = 0; kt < 8; kt++) {
        __syncthreads();                       // prev tile's PV done with rl
        {   // stage rel tile: 128 B contiguous per thread, 8x ds_write_b128
            const float* src = srcq + ((size_t)(kt*64 + sk))*64 + sdh;
            #pragma unroll
            for (int i = 0; i < 8; i++) {
                const float4 v4 = *(const float4*)(src + 4*i);
                *(float4*)(wb + 4*((sc4 + i) ^ skx)) = v4;
            }
        }
        __syncthreads();                       // rl ready

        // ---- phase 1 score: lane = k within tile; rel reads are b128
        const int kg = kt*64 + lane;
        const int kx4 = lane & 15;
        const float* rr = rl + lane*64;
        float sc[4] = {0.f, 0.f, 0.f, 0.f};
        #pragma unroll 4
        for (int d0 = 0; d0 < 64; d0 += 4) {
            const float k0 = kTh[(size_t)(d0+0)*512 + kg];     // coalesced
            const float k1 = kTh[(size_t)(d0+1)*512 + kg];
            const float k2 = kTh[(size_t)(d0+2)*512 + kg];
            const float k3 = kTh[(size_t)(d0+3)*512 + kg];
            #pragma unroll
            for (int qi = 0; qi < 4; qi++) {
                const float4 q4 = *(const float4*)(qh + (size_t)qi*64 + d0); // uniform
                const float4 r4 = *(const float4*)(rr + qi*4096
                                                   + 4*((d0 >> 2) ^ kx4));  // b128
                float a = sc[qi];
                a = fmaf(q4.x, k0, a);  a = fmaf(q4.x, r4.x, a);
                a = fmaf(q4.y, k1, a);  a = fmaf(q4.y, r4.y, a);
                a = fmaf(q4.z, k2, a);  a = fmaf(q4.z, r4.z, a);
                a = fmaf(q4.w, k3, a);  a = fmaf(q4.w, r4.w, a);
                sc[qi] = a;
            }
        }

        // ---- phase 2: online softmax update (wave h owns rows (q0+qi, h))
        float P[4];
        #pragma unroll
        for (int qi = 0; qi < 4; qi++) {
            float S = sc[qi]*0.125f
                    + heads[((size_t)(b*512 + q0 + qi))*512 + kg];
            float mt = S;
            #pragma unroll
            for (int w = 1; w < 64; w <<= 1) mt = fmaxf(mt, __shfl_xor(mt, w));
            const float mn = fmaxf(m[qi], mt);
            const float al = __expf(m[qi] - mn);
            const float p  = __expf(S - mn);
            float ps = p;
            #pragma unroll
            for (int w = 1; w < 64; w <<= 1) ps += __shfl_xor(ps, w);
            s[qi]   = s[qi]*al + ps;
            ctx[qi] = ctx[qi]*al;
            m[qi]   = mn;
            P[qi]   = p;
        }

        // ---- phase 3 PV: lane = d; P broadcast via readlane (SGPR lane idx ok)
        const float* vtile = vfh + (size_t)(kt*64)*64 + lane;
        const int l3 = lane & 3, lc = lane >> 2;
        #pragma unroll 8
        for (int kk = 0; kk < 64; kk++) {
            const float v = vtile[(size_t)kk*64];              // coalesced
            const float* rb = rl + kk*64 + (l3 | ((lc ^ (kk & 15)) << 2));
            #pragma unroll
            for (int qi = 0; qi < 4; qi++) {
                const float pk = __int_as_float(
                    __builtin_amdgcn_readlane(__float_as_int(P[qi]), kk));
                ctx[qi] = fmaf(pk, v + rb[qi*4096], ctx[qi]);
            }
        }
    }

    #pragma unroll
    for (int qi = 0; qi < 4; qi++)
        out[((size_t)(b*512 + q0 + qi))*512 + h*64 + lane] = ctx[qi] / s[qi];
}

// --------------------------------------------------------------- launcher ---
extern "C" void kernel_launch(void* const* d_in, const int* in_sizes, int n_in,
                              void* d_out, int out_size, void* d_ws, size_t ws_size,
                              hipStream_t stream)
{
    (void)in_sizes; (void)n_in; (void)out_size; (void)ws_size;

    const float* hidden = (const float*)d_in[0];
    const float* heads  = (const float*)d_in[1];
    const float* rels   = (const float*)d_in[2];
    const float* Wq = (const float*)d_in[3];
    const float* bq = (const float*)d_in[4];
    const float* Wk = (const float*)d_in[5];
    const float* bk = (const float*)d_in[6];
    const float* Wv = (const float*)d_in[7];
    const float* bv = (const float*)d_in[8];
    float* outF = (float*)d_out;

    float* ws = (float*)d_ws;
    float* qf  = ws;                 // (B,H,L,DH) f32, 4 MB
    float* kTb = ws + 1048576;       // (B,H,DH,L) f32, 4 MB  (transposed K)
    float* vf  = ws + 2097152;       // (B,H,L,DH) f32, 4 MB; total 12 MB

    float* WT = outF;                // 3 MB in d_out, consumed before attn writes

    wtrans<<<dim3(8, 8, 3), 256, 0, stream>>>(Wq, Wk, Wv, WT);
    qkv_gemm<<<dim3(128, 3), 256, 0, stream>>>(hidden, WT, bq, bk, bv, qf, kTb, vf);
    attn_flash<<<dim3(512), 512, 0, stream>>>(qf, kTb, vf, rels, heads, outF);
}